// Round 2
// baseline (514.790 us; speedup 1.0000x reference)
//
#include <hip/hip_runtime.h>

#define NNODES 50000
#define NEDGES 800000
#define HEADS 4
#define CHAN 32
#define FEAT 128
#define NEG_SLOPE 0.02f

// Order-preserving float<->uint transform for atomicMax on floats.
// amax buffer is zero-initialized; ord 0 decodes to -NaN-ish (below all
// finite floats through the ordered encoding), so any real logit wins.
__device__ __forceinline__ unsigned f2ord(float x) {
    unsigned b = __float_as_uint(x);
    return (b & 0x80000000u) ? ~b : (b | 0x80000000u);
}
__device__ __forceinline__ float ord2f(unsigned u) {
    unsigned b = (u & 0x80000000u) ? (u ^ 0x80000000u) : ~u;
    return __uint_as_float(b);
}

// K1: per-node attention projections. a_dst[n,h] = dot(x[n,h,:], W[0:32]),
//     a_src[n,h] = dot(x[n,h,:], W[32:64]).
__global__ void node_proj(const float* __restrict__ x, const float* __restrict__ W,
                          float* __restrict__ adst, float* __restrict__ asrc) {
    int t = blockIdx.x * blockDim.x + threadIdx.x;
    if (t >= NNODES * HEADS) return;
    int n = t >> 2, h = t & 3;
    const float4* xr = (const float4*)(x + (size_t)n * FEAT + h * CHAN);
    const float4* wd = (const float4*)W;
    const float4* ws = (const float4*)(W + CHAN);
    float sd = 0.f, ss = 0.f;
#pragma unroll
    for (int q = 0; q < CHAN / 4; q++) {
        float4 v = xr[q];
        float4 d = wd[q];
        float4 s = ws[q];
        sd += v.x * d.x + v.y * d.y + v.z * d.z + v.w * d.w;
        ss += v.x * s.x + v.y * s.y + v.z * s.z + v.w * s.w;
    }
    adst[t] = sd;
    asrc[t] = ss;
}

// K2: per-(edge,head) leaky-relu logit; atomic segment max into amax[i,h].
__global__ void edge_max(const int* __restrict__ ei,
                         const float* __restrict__ adst, const float* __restrict__ asrc,
                         unsigned* __restrict__ amax) {
    int t = blockIdx.x * blockDim.x + threadIdx.x;
    if (t >= NEDGES * HEADS) return;
    int e = t >> 2, h = t & 3;
    int i = ei[e];
    int j = ei[NEDGES + e];
    float a = adst[i * HEADS + h] + asrc[j * HEADS + h];
    a = (a >= 0.f) ? a : NEG_SLOPE * a;
    atomicMax(amax + i * HEADS + h, f2ord(a));
}

// K3: recompute logit, exp(a - amax[i,h]); atomic segment sum into denom[i,h].
__global__ void edge_sum(const int* __restrict__ ei,
                         const float* __restrict__ adst, const float* __restrict__ asrc,
                         const unsigned* __restrict__ amax,
                         float* __restrict__ denom) {
    int t = blockIdx.x * blockDim.x + threadIdx.x;
    if (t >= NEDGES * HEADS) return;
    int e = t >> 2, h = t & 3;
    int i = ei[e];
    int j = ei[NEDGES + e];
    float a = adst[i * HEADS + h] + asrc[j * HEADS + h];
    a = (a >= 0.f) ? a : NEG_SLOPE * a;
    float ev = __expf(a - ord2f(amax[i * HEADS + h]));
    atomicAdd(denom + i * HEADS + h, ev);
}

// K4: weighted scatter-sum. One thread per (edge, feature). 128 consecutive
// threads cover one edge's full feature row -> coalesced x_j read, cache-line
// local atomics on out[i]. coeff recomputed per-thread from node-level arrays
// (all cache-resident; saves a 12.8 MB per-edge buffer in ws).
__global__ void aggregate(const int* __restrict__ ei,
                          const float* __restrict__ x,
                          const float* __restrict__ adst, const float* __restrict__ asrc,
                          const unsigned* __restrict__ amax,
                          const float* __restrict__ denom,
                          float* __restrict__ out) {
    int t = blockIdx.x * blockDim.x + threadIdx.x;
    if (t >= NEDGES * FEAT) return;   // 102,400,000 < 2^31
    int e = t >> 7;
    int r = t & 127;
    int h = r >> 5;
    int i = ei[e];
    int j = ei[NEDGES + e];
    int ih = i * HEADS + h;
    float a = adst[ih] + asrc[j * HEADS + h];
    a = (a >= 0.f) ? a : NEG_SLOPE * a;
    float coeff = __expf(a - ord2f(amax[ih])) / (denom[ih] + 1e-16f);
    atomicAdd(out + (size_t)i * FEAT + r, x[(size_t)j * FEAT + r] * coeff);
}

extern "C" void kernel_launch(void* const* d_in, const int* in_sizes, int n_in,
                              void* d_out, int out_size, void* d_ws, size_t ws_size,
                              hipStream_t stream) {
    const float* x = (const float*)d_in[0];
    const int* ei = (const int*)d_in[1];   // harness delivers integer inputs as int32; [2,E]: row0=i (targets), row1=j (sources)
    const float* W = (const float*)d_in[2];
    float* out = (float*)d_out;

    // Workspace layout (bytes) — total 3.2 MB:
    //   [0       ,  800000)  a_dst : N*H floats
    //   [800000  , 1600000)  a_src : N*H floats
    //   [1600000 , 2400000)  amax  : N*H uint (ordered encoding; init 0)
    //   [2400000 , 3200000)  denom : N*H floats (init 0)
    char* ws = (char*)d_ws;
    float* adst = (float*)(ws + 0);
    float* asrc = (float*)(ws + 800000);
    unsigned* amax = (unsigned*)(ws + 1600000);
    float* denom = (float*)(ws + 2400000);

    // zero amax+denom (adjacent -> one memset) and the output
    hipMemsetAsync(ws + 1600000, 0, 1600000, stream);
    hipMemsetAsync(d_out, 0, (size_t)out_size * sizeof(float), stream);

    {
        int n = NNODES * HEADS;
        node_proj<<<(n + 255) / 256, 256, 0, stream>>>(x, W, adst, asrc);
    }
    {
        int n = NEDGES * HEADS;
        edge_max<<<(n + 255) / 256, 256, 0, stream>>>(ei, adst, asrc, amax);
        edge_sum<<<(n + 255) / 256, 256, 0, stream>>>(ei, adst, asrc, amax, denom);
    }
    {
        int n = NEDGES * FEAT;
        aggregate<<<(n + 255) / 256, 256, 0, stream>>>(ei, x, adst, asrc, amax, denom, out);
    }
}

// Round 3
// 309.250 us; speedup vs baseline: 1.6646x; 1.6646x over previous
//
#include <hip/hip_runtime.h>

#define NNODES 50000
#define NEDGES 800000
#define HEADS 4
#define CHAN 32
#define FEAT 128
#define NEG_SLOPE 0.02f
#define NBLK 196  // ceil(NNODES/256)

// ---------------- shared (both paths) ----------------

// K1: per-node attention projections. a_dst[n,h] = dot(x[n,h,:], W[0:32]),
//     a_src[n,h] = dot(x[n,h,:], W[32:64]).
__global__ void node_proj(const float* __restrict__ x, const float* __restrict__ W,
                          float* __restrict__ adst, float* __restrict__ asrc) {
    int t = blockIdx.x * blockDim.x + threadIdx.x;
    if (t >= NNODES * HEADS) return;
    int n = t >> 2, h = t & 3;
    const float4* xr = (const float4*)(x + (size_t)n * FEAT + h * CHAN);
    const float4* wd = (const float4*)W;
    const float4* ws = (const float4*)(W + CHAN);
    float sd = 0.f, ss = 0.f;
#pragma unroll
    for (int q = 0; q < CHAN / 4; q++) {
        float4 v = xr[q];
        float4 d = wd[q];
        float4 s = ws[q];
        sd += v.x * d.x + v.y * d.y + v.z * d.z + v.w * d.w;
        ss += v.x * s.x + v.y * s.y + v.z * s.z + v.w * s.w;
    }
    adst[t] = sd;
    asrc[t] = ss;
}

// ---------------- CSR (counting sort) path ----------------

// Histogram of target nodes.
__global__ void hist_targets(const int* __restrict__ ei, int* __restrict__ counts) {
    int e = blockIdx.x * blockDim.x + threadIdx.x;
    if (e >= NEDGES) return;
    atomicAdd(counts + ei[e], 1);
}

// Per-block exclusive scan (Hillis-Steele in LDS); block sums to partials.
__global__ void scan_blocks(const int* __restrict__ counts, int* __restrict__ row_ptr,
                            int* __restrict__ partials) {
    __shared__ int s[256];
    int t = threadIdx.x;
    int g = blockIdx.x * 256 + t;
    int v = (g < NNODES) ? counts[g] : 0;
    s[t] = v;
    __syncthreads();
    for (int off = 1; off < 256; off <<= 1) {
        int add = (t >= off) ? s[t - off] : 0;
        __syncthreads();
        s[t] += add;
        __syncthreads();
    }
    if (g < NNODES) row_ptr[g] = s[t] - v;      // exclusive within block
    if (t == 255) partials[blockIdx.x] = s[255]; // inclusive block total
}

// Exclusive scan of the block partials (one block).
__global__ void scan_partials(int* __restrict__ partials, int nb) {
    __shared__ int s[256];
    int t = threadIdx.x;
    int v = (t < nb) ? partials[t] : 0;
    s[t] = v;
    __syncthreads();
    for (int off = 1; off < 256; off <<= 1) {
        int add = (t >= off) ? s[t - off] : 0;
        __syncthreads();
        s[t] += add;
        __syncthreads();
    }
    if (t < nb) partials[t] = s[t] - v;
}

// row_ptr[n] += partials[block(n)]; cursor = copy; sentinel at NNODES.
__global__ void finalize_rows(int* __restrict__ row_ptr, const int* __restrict__ partials,
                              int* __restrict__ cursor) {
    int n = blockIdx.x * blockDim.x + threadIdx.x;
    if (n == 0) row_ptr[NNODES] = NEDGES;
    if (n >= NNODES) return;
    int r = row_ptr[n] + partials[n >> 8];
    row_ptr[n] = r;
    cursor[n] = r;
}

// Scatter source ids into target-sorted order.
__global__ void scatter_edges(const int* __restrict__ ei, int* __restrict__ cursor,
                              int* __restrict__ sj) {
    int e = blockIdx.x * blockDim.x + threadIdx.x;
    if (e >= NEDGES) return;
    int i = ei[e];
    int pos = atomicAdd(cursor + i, 1);
    sj[pos] = ei[NEDGES + e];
}

// One wave per target node. Lane l owns feats {2l, 2l+1} (head = l>>4).
// Pass 1: register-accumulated softmax denominator (every lane walks all
// segment edges, so each lane's sum IS its head's denom — no cross-lane op).
// Pass 2: gather x_j (coalesced 512B/edge float2 loads), fma, plain store.
// Max-subtraction dropped: logits bounded (~|a|<=12), softmax shift-invariant.
__global__ __launch_bounds__(256) void aggregate_csr(
    const int* __restrict__ row_ptr, const int* __restrict__ sj,
    const float* __restrict__ x,
    const float* __restrict__ adst, const float* __restrict__ asrc,
    float* __restrict__ out) {
    int wave = (blockIdx.x * blockDim.x + threadIdx.x) >> 6;
    int lane = threadIdx.x & 63;
    if (wave >= NNODES) return;
    int i = wave;
    int beg = row_ptr[i], end = row_ptr[i + 1];
    int h = lane >> 4;
    float ad = adst[(i << 2) + h];

    float dsum = 0.f;
    for (int p = beg; p < end; ++p) {
        int j = sj[p];
        float a = ad + asrc[(j << 2) + h];
        a = (a >= 0.f) ? a : NEG_SLOPE * a;
        dsum += __expf(a);
    }
    float inv = 1.f / (dsum + 1e-16f);

    float2 acc = make_float2(0.f, 0.f);
    int p = beg;
    for (; p + 1 < end; p += 2) {  // 2x unroll: two gathers in flight
        int j0 = sj[p], j1 = sj[p + 1];
        float a0 = ad + asrc[(j0 << 2) + h];
        float a1 = ad + asrc[(j1 << 2) + h];
        float2 v0 = *(const float2*)(x + ((size_t)j0 << 7) + (lane << 1));
        float2 v1 = *(const float2*)(x + ((size_t)j1 << 7) + (lane << 1));
        a0 = (a0 >= 0.f) ? a0 : NEG_SLOPE * a0;
        a1 = (a1 >= 0.f) ? a1 : NEG_SLOPE * a1;
        float c0 = __expf(a0) * inv;
        float c1 = __expf(a1) * inv;
        acc.x += v0.x * c0; acc.y += v0.y * c0;
        acc.x += v1.x * c1; acc.y += v1.y * c1;
    }
    if (p < end) {
        int j = sj[p];
        float a = ad + asrc[(j << 2) + h];
        a = (a >= 0.f) ? a : NEG_SLOPE * a;
        float c = __expf(a) * inv;
        float2 v = *(const float2*)(x + ((size_t)j << 7) + (lane << 1));
        acc.x += v.x * c; acc.y += v.y * c;
    }
    *(float2*)(out + ((size_t)i << 7) + (lane << 1)) = acc;
}

// ---------------- fallback (round-2 proven atomic path) ----------------

__device__ __forceinline__ unsigned f2ord(float x) {
    unsigned b = __float_as_uint(x);
    return (b & 0x80000000u) ? ~b : (b | 0x80000000u);
}
__device__ __forceinline__ float ord2f(unsigned u) {
    unsigned b = (u & 0x80000000u) ? (u ^ 0x80000000u) : ~u;
    return __uint_as_float(b);
}

__global__ void edge_max(const int* __restrict__ ei,
                         const float* __restrict__ adst, const float* __restrict__ asrc,
                         unsigned* __restrict__ amax) {
    int t = blockIdx.x * blockDim.x + threadIdx.x;
    if (t >= NEDGES * HEADS) return;
    int e = t >> 2, h = t & 3;
    int i = ei[e];
    int j = ei[NEDGES + e];
    float a = adst[i * HEADS + h] + asrc[j * HEADS + h];
    a = (a >= 0.f) ? a : NEG_SLOPE * a;
    atomicMax(amax + i * HEADS + h, f2ord(a));
}

__global__ void edge_sum(const int* __restrict__ ei,
                         const float* __restrict__ adst, const float* __restrict__ asrc,
                         const unsigned* __restrict__ amax,
                         float* __restrict__ denom) {
    int t = blockIdx.x * blockDim.x + threadIdx.x;
    if (t >= NEDGES * HEADS) return;
    int e = t >> 2, h = t & 3;
    int i = ei[e];
    int j = ei[NEDGES + e];
    float a = adst[i * HEADS + h] + asrc[j * HEADS + h];
    a = (a >= 0.f) ? a : NEG_SLOPE * a;
    float ev = __expf(a - ord2f(amax[i * HEADS + h]));
    atomicAdd(denom + i * HEADS + h, ev);
}

__global__ void aggregate_atomic(const int* __restrict__ ei,
                                 const float* __restrict__ x,
                                 const float* __restrict__ adst, const float* __restrict__ asrc,
                                 const unsigned* __restrict__ amax,
                                 const float* __restrict__ denom,
                                 float* __restrict__ out) {
    int t = blockIdx.x * blockDim.x + threadIdx.x;
    if (t >= NEDGES * FEAT) return;
    int e = t >> 7;
    int r = t & 127;
    int h = r >> 5;
    int i = ei[e];
    int j = ei[NEDGES + e];
    int ih = i * HEADS + h;
    float a = adst[ih] + asrc[j * HEADS + h];
    a = (a >= 0.f) ? a : NEG_SLOPE * a;
    float coeff = __expf(a - ord2f(amax[ih])) / (denom[ih] + 1e-16f);
    atomicAdd(out + (size_t)i * FEAT + r, x[(size_t)j * FEAT + r] * coeff);
}

// ---------------- launcher ----------------

extern "C" void kernel_launch(void* const* d_in, const int* in_sizes, int n_in,
                              void* d_out, int out_size, void* d_ws, size_t ws_size,
                              hipStream_t stream) {
    const float* x = (const float*)d_in[0];
    const int* ei = (const int*)d_in[1];   // int32 [2,E]: row0 = i (targets), row1 = j (sources)
    const float* W = (const float*)d_in[2];
    float* out = (float*)d_out;
    char* ws = (char*)d_ws;

    // CSR layout (bytes):
    //   [0       ,  800000)  a_dst    : N*H f32
    //   [800000  , 1600000)  a_src    : N*H f32
    //   [1600000 , 1800000)  counts   : N i32  (zeroed)
    //   [1800000 , 2000192)  row_ptr  : N+1 i32
    //   [2000192 , 2200192)  cursor   : N i32
    //   [2200192 , 2201216)  partials : NBLK i32
    //   [2201216 , 5401216)  sorted_j : E i32
    const size_t CSR_REQ = 5401216;
    float* adst = (float*)(ws + 0);
    float* asrc = (float*)(ws + 800000);

    if (ws_size >= CSR_REQ) {
        int* counts = (int*)(ws + 1600000);
        int* row_ptr = (int*)(ws + 1800000);
        int* cursor = (int*)(ws + 2000192);
        int* partials = (int*)(ws + 2200192);
        int* sj = (int*)(ws + 2201216);

        hipMemsetAsync(counts, 0, NNODES * sizeof(int), stream);

        node_proj<<<(NNODES * HEADS + 255) / 256, 256, 0, stream>>>(x, W, adst, asrc);
        hist_targets<<<(NEDGES + 255) / 256, 256, 0, stream>>>(ei, counts);
        scan_blocks<<<NBLK, 256, 0, stream>>>(counts, row_ptr, partials);
        scan_partials<<<1, 256, 0, stream>>>(partials, NBLK);
        finalize_rows<<<NBLK, 256, 0, stream>>>(row_ptr, partials, cursor);
        scatter_edges<<<(NEDGES + 255) / 256, 256, 0, stream>>>(ei, cursor, sj);
        // 50000 waves, 4 waves/block -> 12500 blocks; writes every out element.
        aggregate_csr<<<(NNODES + 3) / 4, 256, 0, stream>>>(row_ptr, sj, x, adst, asrc, out);
    } else {
        // fallback: round-2 proven path (3.2 MB ws)
        unsigned* amax = (unsigned*)(ws + 1600000);
        float* denom = (float*)(ws + 2400000);

        hipMemsetAsync(ws + 1600000, 0, 1600000, stream);
        hipMemsetAsync(d_out, 0, (size_t)out_size * sizeof(float), stream);

        node_proj<<<(NNODES * HEADS + 255) / 256, 256, 0, stream>>>(x, W, adst, asrc);
        edge_max<<<(NEDGES * HEADS + 255) / 256, 256, 0, stream>>>(ei, adst, asrc, amax);
        edge_sum<<<(NEDGES * HEADS + 255) / 256, 256, 0, stream>>>(ei, adst, asrc, amax, denom);
        aggregate_atomic<<<(NEDGES * FEAT + 255) / 256, 256, 0, stream>>>(ei, x, adst, asrc, amax, denom, out);
    }
}